// Round 1
// baseline (586.410 us; speedup 1.0000x reference)
//
#include <hip/hip_runtime.h>

#define T_Q 4096
#define S_REAL 8194
#define S_KEYS 8224   // key-loop coverage: 257 tiles * 32
#define S_PAD 8256    // allocated rows for phi_ts / kp / vpo (129*64)
#define SCALE 0.08838834764831843f   // sqrt(1/128) == 1/sqrt(D)
#define NEG_BIG -1.0e30f

typedef __attribute__((ext_vector_type(8))) short short8;
typedef __attribute__((ext_vector_type(4))) float f32x4;

static __device__ __forceinline__ unsigned short f2bf(float f) {
    unsigned int u = __float_as_uint(f);
    u += 0x7FFFu + ((u >> 16) & 1u);
    return (unsigned short)(u >> 16);
}

// ---------------- harmonic encode: phi[row][j] = s*cos(x*f[j]) | s*sin(x*f[j]) ----------
__global__ void encode_kernel(const float* __restrict__ t, const float* __restrict__ ets,
                              const float* __restrict__ bf, unsigned short* __restrict__ phi_t,
                              unsigned short* __restrict__ phi_ts) {
    int tid = threadIdx.x;
    int R = blockIdx.x * 4 + (tid >> 6);
    int j = tid & 63;
    float x; unsigned short* dst;
    if (R < T_Q) { x = t[R]; dst = phi_t + (size_t)R * 128; }
    else {
        int s = R - T_Q;
        x = (s < 2) ? 0.0f : ((s < S_REAL) ? ets[s - 2] : 0.0f); // pad rows: finite garbage (masked later)
        dst = phi_ts + (size_t)s * 128;
    }
    float m = x * bf[j];
    dst[j]      = f2bf(cosf(m) * SCALE);
    dst[64 + j] = f2bf(sinf(m) * SCALE);
}

// ---------------- per-key mask metadata ----------------
__global__ void meta_kernel(const float* __restrict__ ets, const int* __restrict__ exps,
                            const int* __restrict__ tgtp, float* __restrict__ ts_pad,
                            int* __restrict__ match) {
    int s = blockIdx.x * 256 + threadIdx.x;
    if (s >= S_KEYS) return;
    int tgt = tgtp[0];
    float tsv; int m;
    if (s == 0)            { tsv = 0.0f; m = 0; }           // exp=-1 != target
    else if (s == 1)       { tsv = 0.0f; m = 1; }           // exp == target
    else if (s < S_REAL)   { tsv = ets[s - 2]; m = (exps[s - 2] == tgt) ? 1 : 0; }
    else                   { tsv = 3.0e38f; m = 0; }        // pad keys: always time-masked
    ts_pad[s] = tsv; match[s] = m;
}

// ---------------- Wvo = Wo @ Wv, bvo = Wo @ bv (fold output projection into V) ----------
__global__ void wvo_kernel(const float* __restrict__ Wo_s, const float* __restrict__ Wv_s,
                           const float* __restrict__ bv_s,
                           const float* __restrict__ Wo_n, const float* __restrict__ Wv_n,
                           const float* __restrict__ bv_n,
                           float* __restrict__ Wvo, float* __restrict__ bvo) {
    int h = blockIdx.y;
    const float* Wo = h ? Wo_n : Wo_s;
    const float* Wv = h ? Wv_n : Wv_s;
    const float* bv = h ? bv_n : bv_s;
    int row = blockIdx.x, col = threadIdx.x;
    float acc = 0.f;
    for (int jj = 0; jj < 128; ++jj) acc += Wo[row * 128 + jj] * Wv[jj * 128 + col];
    Wvo[h * 16384 + row * 128 + col] = acc;
    __shared__ float red[128];
    red[col] = Wo[row * 128 + col] * bv[col];
    __syncthreads();
    for (int off = 64; off > 0; off >>= 1) { if (col < off) red[col] += red[col + off]; __syncthreads(); }
    if (col == 0) bvo[h * 128 + row] = red[0];
}

// ---------------- pre-convert projection weights to bf16 ----------------
__global__ void prep_w_kernel(const float* __restrict__ Wq_s, const float* __restrict__ Wq_n,
                              const float* __restrict__ Wk_s, const float* __restrict__ Wk_n,
                              const float* __restrict__ Wvo, unsigned short* __restrict__ Wb) {
    int idx = blockIdx.x * 256 + threadIdx.x;  // 6*16384 total
    int which = idx >> 14, e = idx & 16383;
    const float* src;
    switch (which) {
        case 0: src = Wq_s; break; case 1: src = Wq_n; break;
        case 2: src = Wk_s; break; case 3: src = Wk_n; break;
        case 4: src = Wvo;  break; default: src = Wvo + 16384;
    }
    Wb[idx] = f2bf(src[e]);
}

// ---------------- projections: out = in @ W^T + b (bf16 out), MFMA 16x16x32 ----------------
__global__ __launch_bounds__(256) void proj_kernel(
    const unsigned short* __restrict__ phi_t, const unsigned short* __restrict__ phi_ts,
    const unsigned short* __restrict__ Wb,
    const float* __restrict__ bq_s, const float* __restrict__ bq_n,
    const float* __restrict__ bk_s, const float* __restrict__ bk_n,
    const float* __restrict__ bvo,
    unsigned short* __restrict__ qp, unsigned short* __restrict__ kp,
    unsigned short* __restrict__ vpo)
{
    int y = blockIdx.y;
    const unsigned short* in; const float* b; unsigned short* out; int M;
    switch (y) {
        case 0: in = phi_t;  b = bq_s;       out = qp;                         M = T_Q;  break;
        case 1: in = phi_t;  b = bq_n;       out = qp  + (size_t)T_Q  * 128;   M = T_Q;  break;
        case 2: in = phi_ts; b = bk_s;       out = kp;                         M = S_PAD; break;
        case 3: in = phi_ts; b = bk_n;       out = kp  + (size_t)S_PAD * 128;  M = S_PAD; break;
        case 4: in = phi_ts; b = bvo;        out = vpo;                        M = S_PAD; break;
        default:in = phi_ts; b = bvo + 128;  out = vpo + (size_t)S_PAD * 128;  M = S_PAD; break;
    }
    const unsigned short* W = Wb + (size_t)y * 16384;
    int mbase = blockIdx.x * 64 + (int)(threadIdx.x >> 6) * 16;
    if (mbase >= M) return;
    int lane = threadIdx.x & 63;
    int u = lane >> 4, c = lane & 15;
    short8 af[4];
    const unsigned short* arow = in + (size_t)(mbase + c) * 128;
    #pragma unroll
    for (int ks = 0; ks < 4; ++ks) af[ks] = *(const short8*)(arow + ks * 32 + u * 8);
    #pragma unroll
    for (int nt = 0; nt < 8; ++nt) {
        int ncol = nt * 16 + c;
        float bval = b[ncol];
        f32x4 acc = {bval, bval, bval, bval};
        #pragma unroll
        for (int ks = 0; ks < 4; ++ks) {
            short8 bf8 = *(const short8*)(W + ncol * 128 + ks * 32 + u * 8);
            acc = __builtin_amdgcn_mfma_f32_16x16x32_bf16(af[ks], bf8, acc, 0, 0, 0);
        }
        #pragma unroll
        for (int r = 0; r < 4; ++r)
            out[(size_t)(mbase + u * 4 + r) * 128 + ncol] = f2bf(acc[r]);
    }
}

// ---------------- fused masked flash attention (Wo pre-folded into V) ----------------
__global__ __launch_bounds__(256) void attn_kernel(
    const unsigned short* __restrict__ qp, const unsigned short* __restrict__ kp,
    const unsigned short* __restrict__ vpo,
    const float* __restrict__ bo_s, const float* __restrict__ bo_n,
    const float* __restrict__ ts_pad, const int* __restrict__ match,
    const float* __restrict__ tq, float* __restrict__ atten)
{
    int h = blockIdx.y;
    const unsigned short* qph = qp  + (size_t)h * T_Q  * 128;
    const unsigned short* kph = kp  + (size_t)h * S_PAD * 128;
    const unsigned short* vph = vpo + (size_t)h * S_PAD * 128;
    const float* bo = h ? bo_n : bo_s;
    int want = h ? 0 : 1;   // self head needs exp==target; neig head needs exp!=target

    __shared__ __align__(16) unsigned short Kbuf[32 * 128];  // XOR-swizzled
    __shared__ __align__(16) unsigned short Vt[128 * 32];    // transposed [d][key]
    __shared__ __align__(16) unsigned short Pbuf[4][16 * 32];

    int tid = threadIdx.x;
    int w = tid >> 6, lane = tid & 63;
    int u = lane >> 4, c = lane & 15;
    int qrow0 = blockIdx.x * 64 + w * 16;

    short8 qf[4];
    {
        const unsigned short* qr = qph + (size_t)(qrow0 + c) * 128;
        #pragma unroll
        for (int ks = 0; ks < 4; ++ks) qf[ks] = *(const short8*)(qr + ks * 32 + u * 8);
    }
    float t_r[4];
    #pragma unroll
    for (int r = 0; r < 4; ++r) t_r[r] = tq[qrow0 + u * 4 + r];

    f32x4 Ov[8];
    #pragma unroll
    for (int dt = 0; dt < 8; ++dt) Ov[dt] = (f32x4){0.f, 0.f, 0.f, 0.f};
    float mrow[4] = {NEG_BIG, NEG_BIG, NEG_BIG, NEG_BIG};
    float lrow[4] = {0.f, 0.f, 0.f, 0.f};

    int skey = tid >> 3;   // 0..31
    int sch  = tid & 7;    // 0..7

    for (int kt = 0; kt < 257; ++kt) {
        int kbase = kt * 32;
        __syncthreads();
        // --- stage K (swizzled) + V (transposed) ---
        {
            const unsigned short* src = kph + (size_t)(kbase + skey) * 128 + sch * 16;
            short8 v0 = *(const short8*)(src);
            short8 v1 = *(const short8*)(src + 8);
            *(short8*)&Kbuf[skey * 128 + (((sch * 2)     ^ (skey & 7)) << 3)] = v0;
            *(short8*)&Kbuf[skey * 128 + (((sch * 2 + 1) ^ (skey & 7)) << 3)] = v1;
            const unsigned short* vsrc = vph + (size_t)(kbase + skey) * 128 + sch * 16;
            short8 w0 = *(const short8*)(vsrc);
            short8 w1 = *(const short8*)(vsrc + 8);
            #pragma unroll
            for (int jj = 0; jj < 8; ++jj) {
                Vt[(sch * 16 + jj) * 32 + skey]     = (unsigned short)w0[jj];
                Vt[(sch * 16 + 8 + jj) * 32 + skey] = (unsigned short)w1[jj];
            }
        }
        __syncthreads();

        // --- QK^T: two 16-key column tiles ---
        float sc[2][4];
        #pragma unroll
        for (int ct = 0; ct < 2; ++ct) {
            f32x4 acc = {0.f, 0.f, 0.f, 0.f};
            int row = ct * 16 + c;
            #pragma unroll
            for (int ks = 0; ks < 4; ++ks) {
                short8 kf = *(const short8*)&Kbuf[row * 128 + (((ks * 4 + u) ^ (row & 7)) << 3)];
                acc = __builtin_amdgcn_mfma_f32_16x16x32_bf16(qf[ks], kf, acc, 0, 0, 0);
            }
            int key_g = kbase + ct * 16 + c;
            float tsk = ts_pad[key_g];
            bool embad = (match[key_g] != want);
            #pragma unroll
            for (int r = 0; r < 4; ++r) {
                float s = acc[r] * SCALE;
                bool bad = embad || (tsk > t_r[r]);
                sc[ct][r] = bad ? NEG_BIG : s;
            }
        }
        // --- online softmax update ---
        float p[2][4], sf[4];
        #pragma unroll
        for (int r = 0; r < 4; ++r) {
            float mt = fmaxf(sc[0][r], sc[1][r]);
            #pragma unroll
            for (int off = 1; off < 16; off <<= 1) mt = fmaxf(mt, __shfl_xor(mt, off));
            float mnew = fmaxf(mrow[r], mt);
            sf[r] = __expf(mrow[r] - mnew);
            p[0][r] = __expf(sc[0][r] - mnew);
            p[1][r] = __expf(sc[1][r] - mnew);
            float s2 = p[0][r] + p[1][r];
            #pragma unroll
            for (int off = 1; off < 16; off <<= 1) s2 += __shfl_xor(s2, off);
            lrow[r] = lrow[r] * sf[r] + s2;
            mrow[r] = mnew;
        }
        #pragma unroll
        for (int dt = 0; dt < 8; ++dt) {
            Ov[dt][0] *= sf[0]; Ov[dt][1] *= sf[1]; Ov[dt][2] *= sf[2]; Ov[dt][3] *= sf[3];
        }
        // --- P to per-wave LDS tile (swizzled), then PV ---
        #pragma unroll
        for (int ct = 0; ct < 2; ++ct)
            #pragma unroll
            for (int r = 0; r < 4; ++r) {
                int row = u * 4 + r;
                int col = ct * 16 + c;
                Pbuf[w][row * 32 + (col ^ ((row & 3) << 3))] = f2bf(p[ct][r]);
            }
        __asm__ volatile("s_waitcnt lgkmcnt(0)" ::: "memory");
        short8 pf = *(const short8*)&Pbuf[w][c * 32 + ((u ^ (c & 3)) << 3)];
        #pragma unroll
        for (int dt = 0; dt < 8; ++dt) {
            short8 vf = *(const short8*)&Vt[(dt * 16 + c) * 32 + u * 8];
            Ov[dt] = __builtin_amdgcn_mfma_f32_16x16x32_bf16(pf, vf, Ov[dt], 0, 0, 0);
        }
    }

    // --- epilogue: normalize, add (folded) output bias, store fp32 ---
    float rl[4];
    #pragma unroll
    for (int r = 0; r < 4; ++r) rl[r] = 1.0f / lrow[r];
    #pragma unroll
    for (int dt = 0; dt < 8; ++dt) {
        float bv = bo[dt * 16 + c];
        #pragma unroll
        for (int r = 0; r < 4; ++r) {
            int row = qrow0 + u * 4 + r;
            atten[(size_t)row * 256 + h * 128 + dt * 16 + c] = Ov[dt][r] * rl[r] + bv;
        }
    }
}

// ---------------- lambda head: lam = atten @ W_lin^T + b, softplus ----------------
__global__ void lambda_kernel(const float* __restrict__ atten, const float* __restrict__ Wl,
                              const float* __restrict__ bl, const float* __restrict__ phi,
                              float* __restrict__ lambdav) {
    int w = threadIdx.x >> 6, lane = threadIdx.x & 63;
    int row = blockIdx.x * 4 + w;
    f32x4 a  = *(const f32x4*)(atten + (size_t)row * 256 + lane * 4);
    f32x4 wv = *(const f32x4*)(Wl + lane * 4);
    float dot = a[0] * wv[0] + a[1] * wv[1] + a[2] * wv[2] + a[3] * wv[3];
    #pragma unroll
    for (int off = 1; off < 64; off <<= 1) dot += __shfl_xor(dot, off);
    if (lane == 0) {
        float ph = phi[0];
        float x = (dot + bl[0]) * ph;
        x = fminf(x, 20.0f);
        lambdav[row] = log1pf(__expf(x)) / ph;
    }
}

extern "C" void kernel_launch(void* const* d_in, const int* in_sizes, int n_in,
                              void* d_out, int out_size, void* d_ws, size_t ws_size,
                              hipStream_t stream) {
    (void)in_sizes; (void)n_in; (void)out_size; (void)ws_size;
    const float* t    = (const float*)d_in[0];
    const float* ets  = (const float*)d_in[1];
    const int*   exps = (const int*)d_in[2];
    const int*   tgt  = (const int*)d_in[3];
    const float* bfq  = (const float*)d_in[4];
    const float* phi  = (const float*)d_in[5];
    const float* Wlin = (const float*)d_in[6];
    const float* blin = (const float*)d_in[7];
    const float* Wq_s = (const float*)d_in[8];
    const float* Wk_s = (const float*)d_in[9];
    const float* Wv_s = (const float*)d_in[10];
    const float* Wo_s = (const float*)d_in[11];
    const float* bq_s = (const float*)d_in[12];
    const float* bk_s = (const float*)d_in[13];
    const float* bv_s = (const float*)d_in[14];
    const float* bo_s = (const float*)d_in[15];
    const float* Wq_n = (const float*)d_in[16];
    const float* Wk_n = (const float*)d_in[17];
    const float* Wv_n = (const float*)d_in[18];
    const float* Wo_n = (const float*)d_in[19];
    const float* bq_n = (const float*)d_in[20];
    const float* bk_n = (const float*)d_in[21];
    const float* bv_n = (const float*)d_in[22];
    const float* bo_n = (const float*)d_in[23];

    char* ws = (char*)d_ws;
    size_t off = 0;
    auto alloc = [&](size_t bytes) { void* p = ws + off; off += (bytes + 255) & ~(size_t)255; return p; };
    unsigned short* phi_t  = (unsigned short*)alloc((size_t)T_Q  * 128 * 2);
    unsigned short* phi_ts = (unsigned short*)alloc((size_t)S_PAD * 128 * 2);
    unsigned short* qpb    = (unsigned short*)alloc((size_t)2 * T_Q  * 128 * 2);
    unsigned short* kpb    = (unsigned short*)alloc((size_t)2 * S_PAD * 128 * 2);
    unsigned short* vpob   = (unsigned short*)alloc((size_t)2 * S_PAD * 128 * 2);
    float* ts_pad = (float*)alloc((size_t)S_KEYS * 4);
    int*   match  = (int*)  alloc((size_t)S_KEYS * 4);
    float* Wvo    = (float*)alloc((size_t)2 * 16384 * 4);
    float* bvo    = (float*)alloc((size_t)2 * 128 * 4);
    unsigned short* Wb = (unsigned short*)alloc((size_t)6 * 16384 * 2);

    float* outp    = (float*)d_out;
    float* lambdav = outp;
    float* atten   = outp + T_Q;

    encode_kernel<<<dim3((T_Q + S_PAD) / 4), dim3(256), 0, stream>>>(t, ets, bfq, phi_t, phi_ts);
    meta_kernel<<<dim3((S_KEYS + 255) / 256), dim3(256), 0, stream>>>(ets, exps, tgt, ts_pad, match);
    wvo_kernel<<<dim3(128, 2), dim3(128), 0, stream>>>(Wo_s, Wv_s, bv_s, Wo_n, Wv_n, bv_n, Wvo, bvo);
    prep_w_kernel<<<dim3(6 * 16384 / 256), dim3(256), 0, stream>>>(Wq_s, Wq_n, Wk_s, Wk_n, Wvo, Wb);
    proj_kernel<<<dim3(129, 6), dim3(256), 0, stream>>>(phi_t, phi_ts, Wb,
                                                        bq_s, bq_n, bk_s, bk_n, bvo, qpb, kpb, vpob);
    attn_kernel<<<dim3(64, 2), dim3(256), 0, stream>>>(qpb, kpb, vpob, bo_s, bo_n,
                                                       ts_pad, match, t, atten);
    lambda_kernel<<<dim3(T_Q / 4), dim3(256), 0, stream>>>(atten, Wlin, blin, phi, lambdav);
}

// Round 2
// 141.713 us; speedup vs baseline: 4.1380x; 4.1380x over previous
//
#include <hip/hip_runtime.h>

#define T_Q 4096
#define S_TOT 8194
#define S_ALLOC 8256
#define SCALE 0.08838834764831843f   // 1/sqrt(128)
#define NEG_BIG -1.0e30f
#define TS_INF 3.0e38f

typedef __attribute__((ext_vector_type(8))) short short8;
typedef __attribute__((ext_vector_type(4))) float f32x4;
typedef __attribute__((ext_vector_type(4))) unsigned short ush4;
typedef unsigned short ush;

static __device__ __forceinline__ ush f2bf(float f) {
    unsigned int u = __float_as_uint(f);
    u += 0x7FFFu + ((u >> 16) & 1u);
    return (ush)(u >> 16);
}

// ---------------- harmonic encode ----------------
__global__ void encode_kernel(const float* __restrict__ t, const float* __restrict__ ets,
                              const float* __restrict__ bf, ush* __restrict__ phi_t,
                              ush* __restrict__ phi_ts) {
    int tid = threadIdx.x;
    int R = blockIdx.x * 4 + (tid >> 6);
    int j = tid & 63;
    float x; ush* dst;
    if (R < T_Q) { x = t[R]; dst = phi_t + (size_t)R * 128; }
    else {
        int s = R - T_Q;
        x = (s < 2) ? 0.0f : ((s < S_TOT) ? ets[s - 2] : 0.0f);
        dst = phi_ts + (size_t)s * 128;
    }
    float m = x * bf[j];
    dst[j]      = f2bf(cosf(m) * SCALE);
    dst[64 + j] = f2bf(sinf(m) * SCALE);
}

// ---------------- deterministic per-head key compaction (prefix scan) ----------------
__global__ void scan_kernel(const float* __restrict__ ets, const int* __restrict__ exps,
                            const int* __restrict__ tgtp,
                            int* __restrict__ perm0, int* __restrict__ perm1,
                            float* __restrict__ ts0, float* __restrict__ ts1,
                            int* __restrict__ counts) {
    __shared__ int sdata[256];
    __shared__ int bases[2];
    int tid = threadIdx.x;
    if (tid < 2) bases[tid] = 0;
    __syncthreads();
    int tgt = tgtp[0];
    const int NCH = (S_TOT + 255) / 256;
    for (int ch = 0; ch < NCH; ++ch) {
        int s = ch * 256 + tid;
        bool valid = (s < S_TOT);
        int m = 0; float tsv = 0.f;
        if (valid) {
            if (s >= 2) { tsv = ets[s - 2]; m = (exps[s - 2] == tgt) ? 1 : 0; }
            else        { tsv = 0.f;        m = (s == 1) ? 1 : 0; }
        }
        sdata[tid] = valid ? (m | ((1 - m) << 16)) : 0;
        __syncthreads();
        for (int off = 1; off < 256; off <<= 1) {
            int add = (tid >= off) ? sdata[tid - off] : 0;
            __syncthreads();
            sdata[tid] += add;
            __syncthreads();
        }
        int incl = sdata[tid];
        int tot  = sdata[255];
        int b0 = bases[0], b1 = bases[1];
        if (valid) {
            if (m) { int p = b1 + (incl & 0xffff) - 1; perm1[p] = s; ts1[p] = tsv; }
            else   { int p = b0 + (incl >> 16) - 1;    perm0[p] = s; ts0[p] = tsv; }
        }
        __syncthreads();
        if (tid == 0) { bases[0] += (tot >> 16); bases[1] += (tot & 0xffff); }
        __syncthreads();
    }
    int c0 = bases[0], c1 = bases[1];
    if (tid == 0) { counts[0] = c0; counts[1] = c1; }
    for (int i = c0 + tid; i < S_ALLOC; i += 256) { perm0[i] = 0; ts0[i] = TS_INF; }
    for (int i = c1 + tid; i < S_ALLOC; i += 256) { perm1[i] = 0; ts1[i] = TS_INF; }
}

// ---------------- Wvo = Wo @ Wv, bvo = Wo @ bv ----------------
__global__ void wvo_kernel(const float* __restrict__ Wo_s, const float* __restrict__ Wv_s,
                           const float* __restrict__ bv_s,
                           const float* __restrict__ Wo_n, const float* __restrict__ Wv_n,
                           const float* __restrict__ bv_n,
                           float* __restrict__ Wvo, float* __restrict__ bvo) {
    int h = blockIdx.y;
    const float* Wo = h ? Wo_n : Wo_s;
    const float* Wv = h ? Wv_n : Wv_s;
    const float* bv = h ? bv_n : bv_s;
    int row = blockIdx.x, col = threadIdx.x;
    float acc = 0.f;
    for (int jj = 0; jj < 128; ++jj) acc += Wo[row * 128 + jj] * Wv[jj * 128 + col];
    Wvo[h * 16384 + row * 128 + col] = acc;
    __shared__ float red[128];
    red[col] = Wo[row * 128 + col] * bv[col];
    __syncthreads();
    for (int off = 64; off > 0; off >>= 1) { if (col < off) red[col] += red[col + off]; __syncthreads(); }
    if (col == 0) bvo[h * 128 + row] = red[0];
}

// ---------------- weights -> bf16 ----------------
__global__ void prep_w_kernel(const float* __restrict__ Wq_s, const float* __restrict__ Wq_n,
                              const float* __restrict__ Wk_s, const float* __restrict__ Wk_n,
                              const float* __restrict__ Wvo, ush* __restrict__ Wb) {
    int idx = blockIdx.x * 256 + threadIdx.x;
    int which = idx >> 14, e = idx & 16383;
    const float* src;
    switch (which) {
        case 0: src = Wq_s; break; case 1: src = Wq_n; break;
        case 2: src = Wk_s; break; case 3: src = Wk_n; break;
        case 4: src = Wvo;  break; default: src = Wvo + 16384;
    }
    Wb[idx] = f2bf(src[e]);
}

// ---------------- projections (gathered per compacted order; V stored transposed) -------
__global__ __launch_bounds__(256) void proj_kernel(
    const ush* __restrict__ phi_t, const ush* __restrict__ phi_ts, const ush* __restrict__ Wb,
    const float* __restrict__ bq_s, const float* __restrict__ bq_n,
    const float* __restrict__ bk_s, const float* __restrict__ bk_n,
    const float* __restrict__ bvo,
    const int* __restrict__ perm0, const int* __restrict__ perm1, const int* __restrict__ counts,
    ush* __restrict__ qp, ush* __restrict__ kpc, ush* __restrict__ vpoT)
{
    int y = blockIdx.y;
    const float* b; int M; const int* perm = nullptr;
    ush* out = nullptr; ush* outT = nullptr;
    switch (y) {
        case 0: b = bq_s;     M = T_Q; out = qp; break;
        case 1: b = bq_n;     M = T_Q; out = qp + (size_t)T_Q * 128; break;
        case 2: b = bk_s;     M = (counts[1] + 63) & ~63; perm = perm1; out = kpc; break;
        case 3: b = bk_n;     M = (counts[0] + 63) & ~63; perm = perm0; out = kpc + (size_t)S_ALLOC * 128; break;
        case 4: b = bvo;      M = (counts[1] + 63) & ~63; perm = perm1; outT = vpoT; break;
        default:b = bvo + 128;M = (counts[0] + 63) & ~63; perm = perm0; outT = vpoT + (size_t)128 * S_ALLOC; break;
    }
    int mbase = blockIdx.x * 64 + (int)(threadIdx.x >> 6) * 16;
    if (mbase >= M) return;
    int lane = threadIdx.x & 63, u = lane >> 4, c = lane & 15;
    const ush* arow = (y < 2) ? (phi_t + (size_t)(mbase + c) * 128)
                              : (phi_ts + (size_t)perm[mbase + c] * 128);
    short8 af[4];
    #pragma unroll
    for (int ks = 0; ks < 4; ++ks) af[ks] = *(const short8*)(arow + ks * 32 + u * 8);
    const ush* W = Wb + (size_t)y * 16384;
    #pragma unroll
    for (int nt = 0; nt < 8; ++nt) {
        int ncol = nt * 16 + c;
        float bval = b[ncol];
        f32x4 acc = {bval, bval, bval, bval};
        #pragma unroll
        for (int ks = 0; ks < 4; ++ks) {
            short8 bf8 = *(const short8*)(W + ncol * 128 + ks * 32 + u * 8);
            acc = __builtin_amdgcn_mfma_f32_16x16x32_bf16(af[ks], bf8, acc, 0, 0, 0);
        }
        if (outT) {
            ush4 pk;
            #pragma unroll
            for (int r = 0; r < 4; ++r) pk[r] = f2bf(acc[r]);
            *(ush4*)(outT + (size_t)ncol * S_ALLOC + mbase + u * 4) = pk;
        } else {
            #pragma unroll
            for (int r = 0; r < 4; ++r)
                out[(size_t)(mbase + u * 4 + r) * 128 + ncol] = f2bf(acc[r]);
        }
    }
}

// ---------------- flash attention over compacted keys, split-K partials ----------------
__global__ __launch_bounds__(256, 2) void attn_kernel(
    const ush* __restrict__ qp, const ush* __restrict__ kpc, const ush* __restrict__ vpoT,
    const float* __restrict__ ts0, const float* __restrict__ ts1,
    const int* __restrict__ counts, const float* __restrict__ tq,
    float* __restrict__ Opart, float* __restrict__ mpart, float* __restrict__ lpart)
{
    int bid = blockIdx.x;
    int head, seg, qt, slot;
    if (bid < 512) { head = 1; seg = bid & 7; qt = bid >> 3; slot = seg; }   // neighbor
    else           { head = 0; seg = 0;       qt = bid - 512; slot = 8; }    // self
    int cnt = counts[head == 0 ? 1 : 0];
    const ush* kph = kpc  + (head ? (size_t)S_ALLOC * 128 : 0);
    const ush* vph = vpoT + (head ? (size_t)128 * S_ALLOC : 0);
    const ush* qph = qp   + (head ? (size_t)T_Q * 128 : 0);
    const float* tsh = (head == 0) ? ts1 : ts0;
    int NT = (cnt + 63) >> 6;
    int t0, t1;
    if (head) { t0 = (seg * NT) >> 3; t1 = ((seg + 1) * NT) >> 3; }
    else      { t0 = 0; t1 = NT; }

    __shared__ __align__(16) ush K2[2][64 * 128];
    __shared__ __align__(16) ush V2[2][128 * 64];
    __shared__ __align__(16) ush Pb[4][16 * 64];
    __shared__ float tsb[2][64];

    int tid = threadIdx.x, w = tid >> 6, lane = tid & 63, u = lane >> 4, c = lane & 15;
    int qrow0 = qt * 64 + w * 16;

    short8 qf[4];
    {
        const ush* qr = qph + (size_t)(qrow0 + c) * 128;
        #pragma unroll
        for (int ks = 0; ks < 4; ++ks) qf[ks] = *(const short8*)(qr + ks * 32 + u * 8);
    }
    float t_r[4];
    #pragma unroll
    for (int r = 0; r < 4; ++r) t_r[r] = tq[qrow0 + u * 4 + r];

    f32x4 Ov[8];
    #pragma unroll
    for (int dt = 0; dt < 8; ++dt) Ov[dt] = (f32x4){0.f, 0.f, 0.f, 0.f};
    float mrow[4] = {NEG_BIG, NEG_BIG, NEG_BIG, NEG_BIG};
    float lrow[4] = {0.f, 0.f, 0.f, 0.f};

    short8 kreg[4], vreg[4]; float tsreg = 0.f;
    int kr = tid >> 2, kq = tid & 3;      // K staging: row, quad
    int vd = tid >> 1, vh = tid & 1;      // V staging: d-row, half

    auto LOADT = [&](int t) {
        int kb = t * 64;
        const ush* src = kph + (size_t)(kb + kr) * 128 + kq * 32;
        #pragma unroll
        for (int i = 0; i < 4; ++i) kreg[i] = *(const short8*)(src + i * 8);
        const ush* vsrc = vph + (size_t)vd * S_ALLOC + kb + vh * 32;
        #pragma unroll
        for (int i = 0; i < 4; ++i) vreg[i] = *(const short8*)(vsrc + i * 8);
        if (tid < 64) tsreg = tsh[kb + tid];
    };
    auto WRITET = [&](int b) {
        #pragma unroll
        for (int i = 0; i < 4; ++i) {
            int g = kq * 4 + i;
            *(short8*)&K2[b][kr * 128 + ((g ^ (kr & 7)) << 3)] = kreg[i];
        }
        #pragma unroll
        for (int i = 0; i < 4; ++i) {
            int g = vh * 4 + i;
            *(short8*)&V2[b][vd * 64 + ((g ^ (vd & 7)) << 3)] = vreg[i];
        }
        if (tid < 64) tsb[b][tid] = tsreg;
    };

    if (t0 < t1) { LOADT(t0); WRITET(0); }
    __syncthreads();

    for (int t = t0; t < t1; ++t) {
        int cur = (t - t0) & 1;
        bool pre = (t + 1 < t1);
        if (pre) LOADT(t + 1);

        // --- QK^T: four 16-key tiles ---
        float sc[4][4];
        #pragma unroll
        for (int ct = 0; ct < 4; ++ct) {
            f32x4 acc = {0.f, 0.f, 0.f, 0.f};
            int row = ct * 16 + c;
            #pragma unroll
            for (int ks = 0; ks < 4; ++ks) {
                short8 kf = *(const short8*)&K2[cur][row * 128 + (((ks * 4 + u) ^ (row & 7)) << 3)];
                acc = __builtin_amdgcn_mfma_f32_16x16x32_bf16(qf[ks], kf, acc, 0, 0, 0);
            }
            float tsk = tsb[cur][ct * 16 + c];
            #pragma unroll
            for (int r = 0; r < 4; ++r) {
                float s = acc[r] * SCALE;
                sc[ct][r] = (tsk > t_r[r]) ? NEG_BIG : s;
            }
        }
        // --- online softmax ---
        float p[4][4], sf[4];
        #pragma unroll
        for (int r = 0; r < 4; ++r) {
            float mt = fmaxf(fmaxf(sc[0][r], sc[1][r]), fmaxf(sc[2][r], sc[3][r]));
            #pragma unroll
            for (int off = 1; off < 16; off <<= 1) mt = fmaxf(mt, __shfl_xor(mt, off));
            float mnew = fmaxf(mrow[r], mt);
            sf[r] = __expf(mrow[r] - mnew);
            float s4 = 0.f;
            #pragma unroll
            for (int ct = 0; ct < 4; ++ct) { p[ct][r] = __expf(sc[ct][r] - mnew); s4 += p[ct][r]; }
            #pragma unroll
            for (int off = 1; off < 16; off <<= 1) s4 += __shfl_xor(s4, off);
            lrow[r] = lrow[r] * sf[r] + s4;
            mrow[r] = mnew;
        }
        #pragma unroll
        for (int dt = 0; dt < 8; ++dt) {
            Ov[dt][0] *= sf[0]; Ov[dt][1] *= sf[1]; Ov[dt][2] *= sf[2]; Ov[dt][3] *= sf[3];
        }
        // --- P -> per-wave LDS (swizzled) ---
        #pragma unroll
        for (int ct = 0; ct < 4; ++ct)
            #pragma unroll
            for (int r = 0; r < 4; ++r) {
                int prow = u * 4 + r, pcol = ct * 16 + c;
                Pb[w][prow * 64 + ((((pcol >> 3) ^ (prow & 7)) << 3) + (pcol & 7))] = f2bf(p[ct][r]);
            }
        asm volatile("s_waitcnt lgkmcnt(0)" ::: "memory");
        __builtin_amdgcn_sched_barrier(0);
        // --- PV ---
        #pragma unroll
        for (int ksl = 0; ksl < 2; ++ksl) {
            short8 pf = *(const short8*)&Pb[w][c * 64 + (((ksl * 4 + u) ^ (c & 7)) << 3)];
            #pragma unroll
            for (int dt = 0; dt < 8; ++dt) {
                int d = dt * 16 + c;
                short8 vf = *(const short8*)&V2[cur][d * 64 + (((ksl * 4 + u) ^ (d & 7)) << 3)];
                Ov[dt] = __builtin_amdgcn_mfma_f32_16x16x32_bf16(pf, vf, Ov[dt], 0, 0, 0);
            }
        }
        if (pre) WRITET(cur ^ 1);
        __syncthreads();
    }

    // --- write partials ---
    size_t rbase = (size_t)slot * T_Q + qrow0;
    #pragma unroll
    for (int dt = 0; dt < 8; ++dt)
        #pragma unroll
        for (int r = 0; r < 4; ++r)
            Opart[(rbase + u * 4 + r) * 128 + dt * 16 + c] = Ov[dt][r];
    if (c == 0) {
        #pragma unroll
        for (int r = 0; r < 4; ++r) {
            mpart[rbase + u * 4 + r] = mrow[r];
            lpart[rbase + u * 4 + r] = lrow[r];
        }
    }
}

// ---------------- combine partials + output bias + lambda head ----------------
__global__ __launch_bounds__(256) void combine_kernel(
    const float* __restrict__ Opart, const float* __restrict__ mpart, const float* __restrict__ lpart,
    const float* __restrict__ bo_s, const float* __restrict__ bo_n,
    const float* __restrict__ Wl, const float* __restrict__ bl,
    const float* __restrict__ phi, float* __restrict__ outp)
{
    int row = blockIdx.x, tid = threadIdx.x;
    float outv;
    if (tid < 128) {               // self head: single partial (slot 8)
        int d = tid;
        size_t rb = (size_t)8 * T_Q + row;
        outv = Opart[rb * 128 + d] / lpart[rb] + bo_s[d];
    } else {                       // neighbor head: merge 8 partials
        int d = tid - 128;
        float M = NEG_BIG;
        #pragma unroll
        for (int z = 0; z < 8; ++z) M = fmaxf(M, mpart[(size_t)z * T_Q + row]);
        float L = 0.f, O = 0.f;
        #pragma unroll
        for (int z = 0; z < 8; ++z) {
            size_t rb = (size_t)z * T_Q + row;
            float wz = __expf(mpart[rb] - M);
            L += wz * lpart[rb];
            O += wz * Opart[rb * 128 + d];
        }
        outv = O / L + bo_n[d];
    }
    outp[T_Q + (size_t)row * 256 + tid] = outv;

    float dot = outv * Wl[tid];
    #pragma unroll
    for (int off = 1; off < 64; off <<= 1) dot += __shfl_xor(dot, off);
    __shared__ float wsum[4];
    if ((tid & 63) == 0) wsum[tid >> 6] = dot;
    __syncthreads();
    if (tid == 0) {
        float s = wsum[0] + wsum[1] + wsum[2] + wsum[3];
        float ph = phi[0];
        float x = (s + bl[0]) * ph;
        x = fminf(x, 20.0f);
        outp[row] = log1pf(__expf(x)) / ph;
    }
}

extern "C" void kernel_launch(void* const* d_in, const int* in_sizes, int n_in,
                              void* d_out, int out_size, void* d_ws, size_t ws_size,
                              hipStream_t stream) {
    (void)in_sizes; (void)n_in; (void)out_size; (void)ws_size;
    const float* t    = (const float*)d_in[0];
    const float* ets  = (const float*)d_in[1];
    const int*   exps = (const int*)d_in[2];
    const int*   tgt  = (const int*)d_in[3];
    const float* bfq  = (const float*)d_in[4];
    const float* phi  = (const float*)d_in[5];
    const float* Wlin = (const float*)d_in[6];
    const float* blin = (const float*)d_in[7];
    const float* Wq_s = (const float*)d_in[8];
    const float* Wk_s = (const float*)d_in[9];
    const float* Wv_s = (const float*)d_in[10];
    const float* Wo_s = (const float*)d_in[11];
    const float* bq_s = (const float*)d_in[12];
    const float* bk_s = (const float*)d_in[13];
    const float* bv_s = (const float*)d_in[14];
    const float* bo_s = (const float*)d_in[15];
    const float* Wq_n = (const float*)d_in[16];
    const float* Wk_n = (const float*)d_in[17];
    const float* Wv_n = (const float*)d_in[18];
    const float* Wo_n = (const float*)d_in[19];
    const float* bq_n = (const float*)d_in[20];
    const float* bk_n = (const float*)d_in[21];
    const float* bv_n = (const float*)d_in[22];
    const float* bo_n = (const float*)d_in[23];

    char* ws = (char*)d_ws;
    size_t off = 0;
    auto alloc = [&](size_t bytes) { void* p = ws + off; off += (bytes + 255) & ~(size_t)255; return p; };
    ush* phi_t  = (ush*)alloc((size_t)T_Q * 128 * 2);
    ush* phi_ts = (ush*)alloc((size_t)S_ALLOC * 128 * 2);
    ush* qpb    = (ush*)alloc((size_t)2 * T_Q * 128 * 2);
    ush* kpc    = (ush*)alloc((size_t)2 * S_ALLOC * 128 * 2);
    ush* vpoT   = (ush*)alloc((size_t)2 * 128 * S_ALLOC * 2);
    int*   perm0 = (int*)  alloc((size_t)S_ALLOC * 4);
    int*   perm1 = (int*)  alloc((size_t)S_ALLOC * 4);
    float* ts0   = (float*)alloc((size_t)S_ALLOC * 4);
    float* ts1   = (float*)alloc((size_t)S_ALLOC * 4);
    int*   counts= (int*)  alloc(256);
    float* Wvo   = (float*)alloc((size_t)2 * 16384 * 4);
    float* bvo   = (float*)alloc((size_t)2 * 128 * 4);
    ush*   Wb    = (ush*)  alloc((size_t)6 * 16384 * 2);
    float* Opart = (float*)alloc((size_t)9 * T_Q * 128 * 4);
    float* mpart = (float*)alloc((size_t)9 * T_Q * 4);
    float* lpart = (float*)alloc((size_t)9 * T_Q * 4);

    float* outp = (float*)d_out;

    encode_kernel<<<dim3((T_Q + S_ALLOC) / 4), dim3(256), 0, stream>>>(t, ets, bfq, phi_t, phi_ts);
    scan_kernel<<<dim3(1), dim3(256), 0, stream>>>(ets, exps, tgt, perm0, perm1, ts0, ts1, counts);
    wvo_kernel<<<dim3(128, 2), dim3(128), 0, stream>>>(Wo_s, Wv_s, bv_s, Wo_n, Wv_n, bv_n, Wvo, bvo);
    prep_w_kernel<<<dim3(6 * 16384 / 256), dim3(256), 0, stream>>>(Wq_s, Wq_n, Wk_s, Wk_n, Wvo, Wb);
    proj_kernel<<<dim3(129, 6), dim3(256), 0, stream>>>(phi_t, phi_ts, Wb,
                                                        bq_s, bq_n, bk_s, bk_n, bvo,
                                                        perm0, perm1, counts, qpb, kpc, vpoT);
    attn_kernel<<<dim3(576), dim3(256), 0, stream>>>(qpb, kpc, vpoT, ts0, ts1, counts, t,
                                                     Opart, mpart, lpart);
    combine_kernel<<<dim3(T_Q), dim3(256), 0, stream>>>(Opart, mpart, lpart, bo_s, bo_n,
                                                        Wlin, blin, phi, outp);
}

// Round 3
// 96.432 us; speedup vs baseline: 6.0810x; 1.4696x over previous
//
#include <hip/hip_runtime.h>

#define T_Q 4096
#define S_TOT 8194
#define S_ALLOC 8256
#define NSEG 11
#define NSLOT 12
#define SCALE 0.08838834764831843f   // 1/sqrt(128)
#define NEG_BIG -1.0e30f
#define TS_INF 3.0e38f

typedef __attribute__((ext_vector_type(8))) short short8;
typedef __attribute__((ext_vector_type(4))) float f32x4;
typedef __attribute__((ext_vector_type(4))) unsigned short ush4;
typedef unsigned short ush;
typedef unsigned int uint32;

static __device__ __forceinline__ ush f2bf(float f) {
    unsigned int u = __float_as_uint(f);
    u += 0x7FFFu + ((u >> 16) & 1u);
    return (ush)(u >> 16);
}

// ---------------- harmonic encode ----------------
__global__ void encode_kernel(const float* __restrict__ t, const float* __restrict__ ets,
                              const float* __restrict__ bf, ush* __restrict__ phi_t,
                              ush* __restrict__ phi_ts) {
    int tid = threadIdx.x;
    int R = blockIdx.x * 4 + (tid >> 6);
    int j = tid & 63;
    float x; ush* dst;
    if (R < T_Q) { x = t[R]; dst = phi_t + (size_t)R * 128; }
    else {
        int s = R - T_Q;
        x = (s < 2) ? 0.0f : ((s < S_TOT) ? ets[s - 2] : 0.0f);
        dst = phi_ts + (size_t)s * 128;
    }
    float m = x * bf[j];
    dst[j]      = f2bf(cosf(m) * SCALE);
    dst[64 + j] = f2bf(sinf(m) * SCALE);
}

// ---------------- per-head key compaction: ballot-based scan ----------------
__global__ __launch_bounds__(1024) void scan_kernel(
    const float* __restrict__ ets, const int* __restrict__ exps, const int* __restrict__ tgtp,
    int* __restrict__ perm0, int* __restrict__ perm1,
    float* __restrict__ ts0, float* __restrict__ ts1, int* __restrict__ counts) {
    __shared__ int woff[2][16];
    __shared__ int bases[2];
    int tid = threadIdx.x, w = tid >> 6, lane = tid & 63;
    if (tid == 0) { bases[0] = 0; bases[1] = 0; }
    __syncthreads();
    int tgt = tgtp[0];
    for (int ch = 0; ch < 9; ++ch) {
        int s = ch * 1024 + tid;
        bool valid = (s < S_TOT);
        int m = 0; float tsv = 0.f;
        if (valid) {
            if (s >= 2) { tsv = ets[s - 2]; m = (exps[s - 2] == tgt) ? 1 : 0; }
            else        { tsv = 0.f;        m = (s == 1) ? 1 : 0; }
        }
        unsigned long long b1 = __ballot(valid && m);
        unsigned long long b0 = __ballot(valid && !m);
        unsigned long long ltm = (1ull << lane) - 1ull;
        int p0 = __popcll(b0 & ltm), p1 = __popcll(b1 & ltm);
        if (lane == 0) { woff[0][w] = __popcll(b0); woff[1][w] = __popcll(b1); }
        __syncthreads();
        if (tid == 0) {
            int a0 = bases[0], a1 = bases[1];
            #pragma unroll
            for (int i = 0; i < 16; ++i) {
                int t0 = woff[0][i]; woff[0][i] = a0; a0 += t0;
                int t1 = woff[1][i]; woff[1][i] = a1; a1 += t1;
            }
            bases[0] = a0; bases[1] = a1;
        }
        __syncthreads();
        if (valid) {
            if (m) { int pp = woff[1][w] + p1; perm1[pp] = s; ts1[pp] = tsv; }
            else   { int pp = woff[0][w] + p0; perm0[pp] = s; ts0[pp] = tsv; }
        }
        __syncthreads();
    }
    int c0 = bases[0], c1 = bases[1];
    if (tid == 0) { counts[0] = c0; counts[1] = c1; }
    for (int i = c0 + tid; i < S_ALLOC; i += 1024) { perm0[i] = 0; ts0[i] = TS_INF; }
    for (int i = c1 + tid; i < S_ALLOC; i += 1024) { perm1[i] = 0; ts1[i] = TS_INF; }
}

// ---------------- Wvo = Wo @ Wv (bf16 into Wb slots 4/5), bvo = Wo @ bv ----------------
__global__ void wvo_kernel(const float* __restrict__ Wo_s, const float* __restrict__ Wv_s,
                           const float* __restrict__ bv_s,
                           const float* __restrict__ Wo_n, const float* __restrict__ Wv_n,
                           const float* __restrict__ bv_n,
                           ush* __restrict__ Wb, float* __restrict__ bvo) {
    int h = blockIdx.y;
    const float* Wo = h ? Wo_n : Wo_s;
    const float* Wv = h ? Wv_n : Wv_s;
    const float* bv = h ? bv_n : bv_s;
    int row = blockIdx.x, col = threadIdx.x;
    float acc = 0.f;
    for (int jj = 0; jj < 128; ++jj) acc += Wo[row * 128 + jj] * Wv[jj * 128 + col];
    Wb[(size_t)(4 + h) * 16384 + row * 128 + col] = f2bf(acc);
    __shared__ float red[128];
    red[col] = Wo[row * 128 + col] * bv[col];
    __syncthreads();
    for (int off = 64; off > 0; off >>= 1) { if (col < off) red[col] += red[col + off]; __syncthreads(); }
    if (col == 0) bvo[h * 128 + row] = red[0];
}

// ---------------- Wq/Wk -> bf16 (slots 0..3) ----------------
__global__ void prep_w_kernel(const float* __restrict__ Wq_s, const float* __restrict__ Wq_n,
                              const float* __restrict__ Wk_s, const float* __restrict__ Wk_n,
                              ush* __restrict__ Wb) {
    int idx = blockIdx.x * 256 + threadIdx.x;   // 4*16384
    int which = idx >> 14, e = idx & 16383;
    const float* src;
    switch (which) {
        case 0: src = Wq_s; break; case 1: src = Wq_n; break;
        case 2: src = Wk_s; break; default: src = Wk_n; break;
    }
    Wb[idx] = f2bf(src[e]);
}

// ---------------- projections (gathered per compacted order; V stored transposed) -------
__global__ __launch_bounds__(256) void proj_kernel(
    const ush* __restrict__ phi_t, const ush* __restrict__ phi_ts, const ush* __restrict__ Wb,
    const float* __restrict__ bq_s, const float* __restrict__ bq_n,
    const float* __restrict__ bk_s, const float* __restrict__ bk_n,
    const float* __restrict__ bvo,
    const int* __restrict__ perm0, const int* __restrict__ perm1, const int* __restrict__ counts,
    ush* __restrict__ qp, ush* __restrict__ kpc, ush* __restrict__ vpoT)
{
    int y = blockIdx.y;
    const float* b; int M; const int* perm = nullptr;
    ush* out = nullptr; ush* outT = nullptr;
    switch (y) {
        case 0: b = bq_s;     M = T_Q; out = qp; break;
        case 1: b = bq_n;     M = T_Q; out = qp + (size_t)T_Q * 128; break;
        case 2: b = bk_s;     M = (counts[1] + 63) & ~63; perm = perm1; out = kpc; break;
        case 3: b = bk_n;     M = (counts[0] + 63) & ~63; perm = perm0; out = kpc + (size_t)S_ALLOC * 128; break;
        case 4: b = bvo;      M = (counts[1] + 63) & ~63; perm = perm1; outT = vpoT; break;
        default:b = bvo + 128;M = (counts[0] + 63) & ~63; perm = perm0; outT = vpoT + (size_t)128 * S_ALLOC; break;
    }
    int mbase = blockIdx.x * 64 + (int)(threadIdx.x >> 6) * 16;
    if (mbase >= M) return;
    int lane = threadIdx.x & 63, u = lane >> 4, c = lane & 15;
    const ush* arow = (y < 2) ? (phi_t + (size_t)(mbase + c) * 128)
                              : (phi_ts + (size_t)perm[mbase + c] * 128);
    short8 af[4];
    #pragma unroll
    for (int ks = 0; ks < 4; ++ks) af[ks] = *(const short8*)(arow + ks * 32 + u * 8);
    const ush* W = Wb + (size_t)y * 16384;
    #pragma unroll
    for (int nt = 0; nt < 8; ++nt) {
        int ncol = nt * 16 + c;
        float bval = b[ncol];
        f32x4 acc = {bval, bval, bval, bval};
        #pragma unroll
        for (int ks = 0; ks < 4; ++ks) {
            short8 bf8 = *(const short8*)(W + ncol * 128 + ks * 32 + u * 8);
            acc = __builtin_amdgcn_mfma_f32_16x16x32_bf16(af[ks], bf8, acc, 0, 0, 0);
        }
        if (outT) {
            ush4 pk;
            #pragma unroll
            for (int r = 0; r < 4; ++r) pk[r] = f2bf(acc[r]);
            *(ush4*)(outT + (size_t)ncol * S_ALLOC + mbase + u * 4) = pk;
        } else {
            #pragma unroll
            for (int r = 0; r < 4; ++r)
                out[(size_t)(mbase + u * 4 + r) * 128 + ncol] = f2bf(acc[r]);
        }
    }
}

// ---------------- flash attention: swapped QK^T, in-register softmax ----------------
__global__ __launch_bounds__(256, 3) void attn_kernel(
    const ush* __restrict__ qp, const ush* __restrict__ kpc, const ush* __restrict__ vpoT,
    const float* __restrict__ ts0, const float* __restrict__ ts1,
    const int* __restrict__ counts, const float* __restrict__ tq,
    float* __restrict__ Opart, float* __restrict__ mpart, float* __restrict__ lpart)
{
    int bid = blockIdx.x;
    int head, seg, qt, slot;
    if (bid < NSEG * 64) { head = 1; seg = bid % NSEG; qt = bid / NSEG; slot = seg; }
    else                 { head = 0; seg = 0; qt = bid - NSEG * 64; slot = NSEG; }
    int cnt = counts[head == 0 ? 1 : 0];
    const ush* kph = kpc  + (head ? (size_t)S_ALLOC * 128 : 0);
    const ush* vph = vpoT + (head ? (size_t)128 * S_ALLOC : 0);
    const ush* qph = qp   + (head ? (size_t)T_Q * 128 : 0);
    const float* tsh = (head == 0) ? ts1 : ts0;
    int NT = (cnt + 63) >> 6;
    int t0, t1;
    if (head) { t0 = seg * NT / NSEG; t1 = (seg + 1) * NT / NSEG; }
    else      { t0 = 0; t1 = NT; }

    __shared__ __align__(16) ush K2[2][64 * 128];   // XOR-swizzled, double-buffered
    __shared__ __align__(16) ush V1[128 * 64];      // transposed [d][key], single buffer
    __shared__ float tsb[2][64];

    int tid = threadIdx.x, w = tid >> 6, lane = tid & 63;
    int u = lane >> 4, c = lane & 15;   // u doubles as the g-group in QK^T-swapped layout
    int qrow0 = qt * 64 + w * 16;

    short8 qf[4];
    {
        const ush* qr = qph + (size_t)(qrow0 + c) * 128;
        #pragma unroll
        for (int ks = 0; ks < 4; ++ks) qf[ks] = *(const short8*)(qr + ks * 32 + u * 8);
    }
    float t_c = tq[qrow0 + c];   // this lane's query time

    f32x4 Ov[8];
    #pragma unroll
    for (int dt = 0; dt < 8; ++dt) Ov[dt] = (f32x4){0.f, 0.f, 0.f, 0.f};
    float mrow = NEG_BIG, lrow = 0.f;

    short8 kreg[4], vreg[4]; float tsreg = 0.f;
    int kr = tid >> 2, kq = tid & 3;
    int vd = tid >> 1, vh = tid & 1;
    int sbase = (lane & 48) + ((lane & 48) >> 2);   // bpermute source base for sf broadcast

    auto LOADT = [&](int t) {
        int kb = t * 64;
        const ush* src = kph + (size_t)(kb + kr) * 128 + kq * 32;
        #pragma unroll
        for (int i = 0; i < 4; ++i) kreg[i] = *(const short8*)(src + i * 8);
        const ush* vsrc = vph + (size_t)vd * S_ALLOC + kb + vh * 32;
        #pragma unroll
        for (int i = 0; i < 4; ++i) vreg[i] = *(const short8*)(vsrc + i * 8);
        if (tid < 64) tsreg = tsh[kb + tid];
    };
    auto WRITE_K = [&](int b) {
        #pragma unroll
        for (int i = 0; i < 4; ++i)
            *(short8*)&K2[b][kr * 128 + (((kq * 4 + i) ^ (kr & 7)) << 3)] = kreg[i];
        if (tid < 64) tsb[b][tid] = tsreg;
    };
    auto WRITE_V = [&]() {
        #pragma unroll
        for (int i = 0; i < 4; ++i)
            *(short8*)&V1[vd * 64 + (((vh * 4 + i) ^ (vd & 7)) << 3)] = vreg[i];
    };

    if (t0 < t1) { LOADT(t0); WRITE_K(0); WRITE_V(); }
    __syncthreads();

    for (int t = t0; t < t1; ++t) {
        int cur = (t - t0) & 1;
        bool pre = (t + 1 < t1);
        if (pre) LOADT(t + 1);

        // --- QK^T swapped: D[key][query], lane owns query c, keys ct*16+u*4+r ---
        float sc[4][4];
        #pragma unroll
        for (int ct = 0; ct < 4; ++ct) {
            f32x4 acc = {0.f, 0.f, 0.f, 0.f};
            int row = ct * 16 + c;
            #pragma unroll
            for (int ks = 0; ks < 4; ++ks) {
                short8 kf = *(const short8*)&K2[cur][row * 128 + (((ks * 4 + u) ^ (row & 7)) << 3)];
                acc = __builtin_amdgcn_mfma_f32_16x16x32_bf16(kf, qf[ks], acc, 0, 0, 0);
            }
            f32x4 ts4 = *(const f32x4*)&tsb[cur][ct * 16 + u * 4];
            #pragma unroll
            for (int r = 0; r < 4; ++r)
                sc[ct][r] = (ts4[r] > t_c) ? NEG_BIG : acc[r] * SCALE;
        }
        if (pre) WRITE_K(cur ^ 1);   // dbuf: safe while others read K2[cur]

        // --- in-register online softmax (per-lane = per-query) ---
        float mt = sc[0][0];
        #pragma unroll
        for (int ct = 0; ct < 4; ++ct)
            #pragma unroll
            for (int r = 0; r < 4; ++r) mt = fmaxf(mt, sc[ct][r]);
        mt = fmaxf(mt, __shfl_xor(mt, 16));
        mt = fmaxf(mt, __shfl_xor(mt, 32));
        if (__any(mt > mrow)) {
            float mnew = fmaxf(mrow, mt);
            float sf = __expf(mrow - mnew);
            mrow = mnew;
            lrow *= sf;
            float sfr[4];
            #pragma unroll
            for (int r = 0; r < 4; ++r) sfr[r] = __shfl(sf, sbase + r);
            #pragma unroll
            for (int dt = 0; dt < 8; ++dt) {
                Ov[dt][0] *= sfr[0]; Ov[dt][1] *= sfr[1];
                Ov[dt][2] *= sfr[2]; Ov[dt][3] *= sfr[3];
            }
        }
        float p[4][4];
        float s16 = 0.f;
        #pragma unroll
        for (int ct = 0; ct < 4; ++ct)
            #pragma unroll
            for (int r = 0; r < 4; ++r) { p[ct][r] = __expf(sc[ct][r] - mrow); s16 += p[ct][r]; }
        s16 += __shfl_xor(s16, 16);
        s16 += __shfl_xor(s16, 32);
        lrow += s16;

        // --- P: cvt_pk to bf16 pairs, permlane exchange into A-fragment layout ---
        uint32 q0[4], q1[4];
        #pragma unroll
        for (int ct = 0; ct < 4; ++ct) {
            asm("v_cvt_pk_bf16_f32 %0, %1, %2" : "=v"(q0[ct]) : "v"(p[ct][0]), "v"(p[ct][1]));
            asm("v_cvt_pk_bf16_f32 %0, %1, %2" : "=v"(q1[ct]) : "v"(p[ct][2]), "v"(p[ct][3]));
        }
        short8 pf[2];
        #pragma unroll
        for (int ksl = 0; ksl < 2; ++ksl) {
            uint32 a0 = q0[2 * ksl], b0 = q0[2 * ksl + 1];
            uint32 a1 = q1[2 * ksl], b1 = q1[2 * ksl + 1];
            asm("v_permlane32_swap_b32 %0, %1" : "+v"(a0), "+v"(b0));
            asm("v_permlane16_swap_b32 %0, %1" : "+v"(a0), "+v"(b0));
            asm("v_permlane32_swap_b32 %0, %1" : "+v"(a1), "+v"(b1));
            asm("v_permlane16_swap_b32 %0, %1" : "+v"(a1), "+v"(b1));
            union { uint32 w4[4]; short8 s8; } pk_;
            pk_.w4[0] = a0; pk_.w4[1] = a1; pk_.w4[2] = b0; pk_.w4[3] = b1;
            pf[ksl] = pk_.s8;
        }

        // --- PV ---
        #pragma unroll
        for (int ksl = 0; ksl < 2; ++ksl)
            #pragma unroll
            for (int dt = 0; dt < 8; ++dt) {
                int d = dt * 16 + c;
                short8 vf = *(const short8*)&V1[d * 64 + (((ksl * 4 + u) ^ (d & 7)) << 3)];
                Ov[dt] = __builtin_amdgcn_mfma_f32_16x16x32_bf16(pf[ksl], vf, Ov[dt], 0, 0, 0);
            }

        __syncthreads();           // all waves done reading V1
        if (pre) WRITE_V();        // overwrite single V buffer with next tile
        __syncthreads();           // V1 ready
    }

    // --- partials ---
    size_t rbase = (size_t)slot * T_Q + qrow0;
    #pragma unroll
    for (int dt = 0; dt < 8; ++dt)
        #pragma unroll
        for (int r = 0; r < 4; ++r)
            Opart[(rbase + u * 4 + r) * 128 + dt * 16 + c] = Ov[dt][r];
    if (lane < 16) {
        mpart[rbase + lane] = mrow;
        lpart[rbase + lane] = lrow;
    }
}

// ---------------- combine partials + output bias + lambda head ----------------
__global__ __launch_bounds__(256) void combine_kernel(
    const float* __restrict__ Opart, const float* __restrict__ mpart, const float* __restrict__ lpart,
    const float* __restrict__ bo_s, const float* __restrict__ bo_n,
    const float* __restrict__ Wl, const float* __restrict__ bl,
    const float* __restrict__ phi, float* __restrict__ outp)
{
    int row = blockIdx.x, tid = threadIdx.x;
    float outv;
    if (tid < 128) {               // self head: single partial (slot NSEG)
        size_t rb = (size_t)NSEG * T_Q + row;
        outv = Opart[rb * 128 + tid] / lpart[rb] + bo_s[tid];
    } else {                       // neighbor head: merge NSEG partials
        int d = tid - 128;
        float M = NEG_BIG;
        #pragma unroll
        for (int z = 0; z < NSEG; ++z) M = fmaxf(M, mpart[(size_t)z * T_Q + row]);
        float L = 0.f, O = 0.f;
        #pragma unroll
        for (int z = 0; z < NSEG; ++z) {
            size_t rb = (size_t)z * T_Q + row;
            float wz = __expf(mpart[rb] - M);
            L += wz * lpart[rb];
            O += wz * Opart[rb * 128 + d];
        }
        outv = O / L + bo_n[d];
    }
    outp[T_Q + (size_t)row * 256 + tid] = outv;

    float dot = outv * Wl[tid];
    #pragma unroll
    for (int off = 1; off < 64; off <<= 1) dot += __shfl_xor(dot, off);
    __shared__ float wsum[4];
    if ((tid & 63) == 0) wsum[tid >> 6] = dot;
    __syncthreads();
    if (tid == 0) {
        float s = wsum[0] + wsum[1] + wsum[2] + wsum[3];
        float ph = phi[0];
        float x = (s + bl[0]) * ph;
        x = fminf(x, 20.0f);
        outp[row] = log1pf(__expf(x)) / ph;
    }
}

extern "C" void kernel_launch(void* const* d_in, const int* in_sizes, int n_in,
                              void* d_out, int out_size, void* d_ws, size_t ws_size,
                              hipStream_t stream) {
    (void)in_sizes; (void)n_in; (void)out_size; (void)ws_size;
    const float* t    = (const float*)d_in[0];
    const float* ets  = (const float*)d_in[1];
    const int*   exps = (const int*)d_in[2];
    const int*   tgt  = (const int*)d_in[3];
    const float* bfq  = (const float*)d_in[4];
    const float* phi  = (const float*)d_in[5];
    const float* Wlin = (const float*)d_in[6];
    const float* blin = (const float*)d_in[7];
    const float* Wq_s = (const float*)d_in[8];
    const float* Wk_s = (const float*)d_in[9];
    const float* Wv_s = (const float*)d_in[10];
    const float* Wo_s = (const float*)d_in[11];
    const float* bq_s = (const float*)d_in[12];
    const float* bk_s = (const float*)d_in[13];
    const float* bv_s = (const float*)d_in[14];
    const float* bo_s = (const float*)d_in[15];
    const float* Wq_n = (const float*)d_in[16];
    const float* Wk_n = (const float*)d_in[17];
    const float* Wv_n = (const float*)d_in[18];
    const float* Wo_n = (const float*)d_in[19];
    const float* bq_n = (const float*)d_in[20];
    const float* bk_n = (const float*)d_in[21];
    const float* bv_n = (const float*)d_in[22];
    const float* bo_n = (const float*)d_in[23];

    char* ws = (char*)d_ws;
    size_t off = 0;
    auto alloc = [&](size_t bytes) { void* p = ws + off; off += (bytes + 255) & ~(size_t)255; return p; };
    ush* phi_t  = (ush*)alloc((size_t)T_Q * 128 * 2);
    ush* phi_ts = (ush*)alloc((size_t)S_ALLOC * 128 * 2);
    ush* qpb    = (ush*)alloc((size_t)2 * T_Q * 128 * 2);
    ush* kpc    = (ush*)alloc((size_t)2 * S_ALLOC * 128 * 2);
    ush* vpoT   = (ush*)alloc((size_t)2 * 128 * S_ALLOC * 2);
    int*   perm0 = (int*)  alloc((size_t)S_ALLOC * 4);
    int*   perm1 = (int*)  alloc((size_t)S_ALLOC * 4);
    float* ts0   = (float*)alloc((size_t)S_ALLOC * 4);
    float* ts1   = (float*)alloc((size_t)S_ALLOC * 4);
    int*   counts= (int*)  alloc(256);
    float* bvo   = (float*)alloc((size_t)2 * 128 * 4);
    ush*   Wb    = (ush*)  alloc((size_t)6 * 16384 * 2);
    float* Opart = (float*)alloc((size_t)NSLOT * T_Q * 128 * 4);
    float* mpart = (float*)alloc((size_t)NSLOT * T_Q * 4);
    float* lpart = (float*)alloc((size_t)NSLOT * T_Q * 4);

    float* outp = (float*)d_out;

    encode_kernel<<<dim3((T_Q + S_ALLOC) / 4), dim3(256), 0, stream>>>(t, ets, bfq, phi_t, phi_ts);
    scan_kernel<<<dim3(1), dim3(1024), 0, stream>>>(ets, exps, tgt, perm0, perm1, ts0, ts1, counts);
    wvo_kernel<<<dim3(128, 2), dim3(128), 0, stream>>>(Wo_s, Wv_s, bv_s, Wo_n, Wv_n, bv_n, Wb, bvo);
    prep_w_kernel<<<dim3(256), dim3(256), 0, stream>>>(Wq_s, Wq_n, Wk_s, Wk_n, Wb);
    proj_kernel<<<dim3(129, 6), dim3(256), 0, stream>>>(phi_t, phi_ts, Wb,
                                                        bq_s, bq_n, bk_s, bk_n, bvo,
                                                        perm0, perm1, counts, qpb, kpc, vpoT);
    attn_kernel<<<dim3(NSEG * 64 + 64), dim3(256), 0, stream>>>(qpb, kpc, vpoT, ts0, ts1, counts, t,
                                                                Opart, mpart, lpart);
    combine_kernel<<<dim3(T_Q), dim3(256), 0, stream>>>(Opart, mpart, lpart, bo_s, bo_n,
                                                        Wlin, blin, phi, outp);
}